// Round 12
// baseline (2052.923 us; speedup 1.0000x reference)
//
#include <hip/hip_runtime.h>

#define NROWS 32768
#define DDIM  512
#define KCENT 8192

// out layout (floats): qout[16777216] loss[16777216] idx[32768] cbv[4194304] counts[8192]
#define O_LOSS 16777216
#define O_IDX  33554432
#define O_CBV  33587200
#define O_CNT  37781504

typedef float f32x4 __attribute__((ext_vector_type(4)));
typedef _Float16 f16x8 __attribute__((ext_vector_type(8)));

// ---- kernel 0: fp32 -> f16, 8-slot XOR pre-swizzle within each 128B K-chunk ----
// slot u of (row r, chunk dk) holds logical unit u^(r&7)
__global__ __launch_bounds__(256) void vq_cvt_swz8(
    const float* __restrict__ src, char* __restrict__ dst)
{
    const int gid = blockIdx.x * 256 + threadIdx.x;   // one 16B f16 unit (8 floats)
    const int r = gid >> 6, w = gid & 63, dk = w >> 3, u = w & 7;
    const float4* p = (const float4*)(src + (size_t)r * DDIM + (dk*8 + (u ^ (r & 7))) * 8);
    float4 a = p[0], b = p[1];
    f16x8 h;
    h[0]=(_Float16)a.x; h[1]=(_Float16)a.y; h[2]=(_Float16)a.z; h[3]=(_Float16)a.w;
    h[4]=(_Float16)b.x; h[5]=(_Float16)b.y; h[6]=(_Float16)b.z; h[7]=(_Float16)b.w;
    *(f16x8*)(dst + (size_t)gid * 16) = h;
}

// ---- kernel 1: centroid squared norms (fp64 accumulate) + counts=1 ----
__global__ __launch_bounds__(256) void vq_cnorm_kernel(
    const float* __restrict__ CB, float* __restrict__ cnorm, float* __restrict__ counts)
{
    const int wid  = threadIdx.x >> 6;
    const int lane = threadIdx.x & 63;
    const int cid  = blockIdx.x * 4 + wid;
    const float4* p = (const float4*)(CB + (size_t)cid * DDIM + lane * 8);
    float4 a = p[0], b = p[1];
    double s = (double)a.x*a.x + (double)a.y*a.y + (double)a.z*a.z + (double)a.w*a.w
             + (double)b.x*b.x + (double)b.y*b.y + (double)b.z*b.z + (double)b.w*b.w;
    #pragma unroll
    for (int off = 32; off > 0; off >>= 1) s += __shfl_down(s, off);
    if (lane == 0) { cnorm[cid] = (float)s; counts[cid] = 1.0f; }
}

__device__ __forceinline__ void t2_update(float s, int c,
                                          float& v1, int& i1, float& v2, int& i2)
{
    if (s < v1)      { v2 = v1; i2 = i1; v1 = s; i1 = c; }
    else if (s < v2) { v2 = s;  i2 = c; }
}

__device__ __forceinline__ void t2_merge(float b1, int bi1, float b2, int bi2,
                                         float& a1, int& ai1, float& a2, int& ai2)
{
    if (b1 < a1 || (b1 == a1 && bi1 < ai1)) {
        float o1 = a1; int oi1 = ai1;
        a1 = b1; ai1 = bi1;
        if (b2 < o1 || (b2 == o1 && bi2 < oi1)) { a2 = b2; ai2 = bi2; }
        else                                    { a2 = o1; ai2 = oi1; }
    } else {
        if (b1 < a2 || (b1 == a2 && bi1 < ai2)) { a2 = b1; ai2 = bi1; }
    }
}

__device__ __forceinline__ void gl16(const char* g, const char* l)
{
    __builtin_amdgcn_global_load_lds(
        (const __attribute__((address_space(1))) void*)g,
        (__attribute__((address_space(3))) void*)l, 16, 0, 0);
}

// ---- kernel 2: sweep GEMM: 64 rows x ALL 8192 cols per block ----
// 512 thr = 8 waves, each 64 rows x 64 cols (m4 x n4 @ 16x16x32 f16).
// A tile (64x512) LDS-resident (staged once); B 32KB/phase dbuf, counted vmcnt(4);
// 256 phases (16 col-sweeps x 16 K-phases); per-sweep reg t2; one final merge.
__global__ __launch_bounds__(512, 2) void vq_sweep_kernel(
    const char* __restrict__ Xf, const char* __restrict__ Cf,
    const float* __restrict__ cnorm, int* __restrict__ pmini2)
{
    __shared__ __align__(16) char lds[131072];  // A 64KB | B0 32KB | B1 32KB

    const int rb   = blockIdx.x;       // 64-row tile index
    const int t    = threadIdx.x;
    const int lane = t & 63;
    const int cg   = t >> 6;           // 8 col-groups of 64
    const int l15  = lane & 15;
    const int lg   = lane >> 4;

    // ---- prologue: stage A tile (64 rows x 512 d = 64KB, linear copy of swz8) ----
    #pragma unroll
    for (int i = 0; i < 8; ++i) {
        const int d = i*512 + t;
        gl16(Xf + (size_t)(rb*64 + (d >> 6))*1024 + (d & 63)*16, &lds[d*16]);
    }

    // B stage: phase buf layout [c 0..511][vpos 0..3] of 16B units;
    // position vpos holds logical k-unit vpos ^ ((c>>1)&3)  (bank-spread swizzle)
    #define STAGE_B(P1, buf) {                                                    \
        const int s1_ = (P1) >> 4, k1_ = (P1) & 15;                               \
        _Pragma("unroll")                                                         \
        for (int i = 0; i < 4; ++i) {                                             \
            const int d_ = i*512 + t;                                             \
            const int c_ = d_ >> 2;                                               \
            const int v_ = (d_ & 3) ^ ((c_ >> 1) & 3);                            \
            const int U_ = k1_*4 + v_;                                            \
            gl16(Cf + (size_t)(s1_*512 + c_)*1024 + (U_ >> 3)*128                 \
                    + (((U_ & 7) ^ (c_ & 7)) * 16),                               \
                 &lds[65536 + (buf)*32768 + d_*16]);                              \
        } }

    STAGE_B(0, 0);
    __syncthreads();   // drains prologue loads (compiler vmcnt(0)) — once only

    // loop-invariant read offsets
    int aro[4], arx[4], bof[4];
    #pragma unroll
    for (int m = 0; m < 4; ++m) {
        const int r = m*16 + l15;
        aro[m] = r*1024;
        arx[m] = r & 7;
    }
    #pragma unroll
    for (int n = 0; n < 4; ++n) {
        const int c = cg*64 + n*16 + l15;
        bof[n] = c*64 + ((lg ^ ((c >> 1) & 3)) * 16);
    }

    f32x4 acc[4][4];
    float rv1[4][4], rv2[4][4];
    int   ri1[4][4], ri2[4][4];
    #pragma unroll
    for (int m = 0; m < 4; ++m)
        #pragma unroll
        for (int n = 0; n < 4; ++n) {
            f32x4 z = {0.f,0.f,0.f,0.f};
            acc[m][n] = z;
            rv1[m][n] = 3.4e38f; rv2[m][n] = 3.4e38f;
            ri1[m][n] = 0x7fffffff; ri2[m][n] = 0x7fffffff;
        }

    for (int P = 0; P < 256; ++P) {
        if (P + 1 < 256) {
            STAGE_B(P + 1, (P + 1) & 1);
            // drain phase-P's 4 loads (issued a full phase ago); keep P+1's in flight
            asm volatile("s_waitcnt vmcnt(4)\n\ts_barrier" ::: "memory");
        } else {
            asm volatile("s_waitcnt vmcnt(0)\n\ts_barrier" ::: "memory");
        }
        const int k = P & 15;
        const char* bb = &lds[65536 + (P & 1)*32768];
        const int kb  = (k >> 1)*128;
        const int sub = (k & 1)*4 + lg;
        f16x8 A0 = *(const f16x8*)(&lds[aro[0] + kb + ((sub ^ arx[0]) * 16)]);
        f16x8 A1 = *(const f16x8*)(&lds[aro[1] + kb + ((sub ^ arx[1]) * 16)]);
        f16x8 A2 = *(const f16x8*)(&lds[aro[2] + kb + ((sub ^ arx[2]) * 16)]);
        f16x8 A3 = *(const f16x8*)(&lds[aro[3] + kb + ((sub ^ arx[3]) * 16)]);
        f16x8 B0 = *(const f16x8*)(bb + bof[0]);
        f16x8 B1 = *(const f16x8*)(bb + bof[1]);
        f16x8 B2 = *(const f16x8*)(bb + bof[2]);
        f16x8 B3 = *(const f16x8*)(bb + bof[3]);
        acc[0][0] = __builtin_amdgcn_mfma_f32_16x16x32_f16(A0, B0, acc[0][0], 0, 0, 0);
        acc[0][1] = __builtin_amdgcn_mfma_f32_16x16x32_f16(A0, B1, acc[0][1], 0, 0, 0);
        acc[0][2] = __builtin_amdgcn_mfma_f32_16x16x32_f16(A0, B2, acc[0][2], 0, 0, 0);
        acc[0][3] = __builtin_amdgcn_mfma_f32_16x16x32_f16(A0, B3, acc[0][3], 0, 0, 0);
        acc[1][0] = __builtin_amdgcn_mfma_f32_16x16x32_f16(A1, B0, acc[1][0], 0, 0, 0);
        acc[1][1] = __builtin_amdgcn_mfma_f32_16x16x32_f16(A1, B1, acc[1][1], 0, 0, 0);
        acc[1][2] = __builtin_amdgcn_mfma_f32_16x16x32_f16(A1, B2, acc[1][2], 0, 0, 0);
        acc[1][3] = __builtin_amdgcn_mfma_f32_16x16x32_f16(A1, B3, acc[1][3], 0, 0, 0);
        acc[2][0] = __builtin_amdgcn_mfma_f32_16x16x32_f16(A2, B0, acc[2][0], 0, 0, 0);
        acc[2][1] = __builtin_amdgcn_mfma_f32_16x16x32_f16(A2, B1, acc[2][1], 0, 0, 0);
        acc[2][2] = __builtin_amdgcn_mfma_f32_16x16x32_f16(A2, B2, acc[2][2], 0, 0, 0);
        acc[2][3] = __builtin_amdgcn_mfma_f32_16x16x32_f16(A2, B3, acc[2][3], 0, 0, 0);
        acc[3][0] = __builtin_amdgcn_mfma_f32_16x16x32_f16(A3, B0, acc[3][0], 0, 0, 0);
        acc[3][1] = __builtin_amdgcn_mfma_f32_16x16x32_f16(A3, B1, acc[3][1], 0, 0, 0);
        acc[3][2] = __builtin_amdgcn_mfma_f32_16x16x32_f16(A3, B2, acc[3][2], 0, 0, 0);
        acc[3][3] = __builtin_amdgcn_mfma_f32_16x16x32_f16(A3, B3, acc[3][3], 0, 0, 0);
        asm volatile("s_barrier" ::: "memory");   // reads done before buf restage

        if (k == 15) {
            // per-sweep epilogue: score = ||c||^2 - 2*dot ; running top-2 (in-reg)
            const int s = P >> 4;
            #pragma unroll
            for (int n = 0; n < 4; ++n) {
                const int col = s*512 + cg*64 + n*16 + l15;
                const float cn = cnorm[col];
                #pragma unroll
                for (int m = 0; m < 4; ++m) {
                    #pragma unroll
                    for (int j = 0; j < 4; ++j) {
                        const float sv = fmaf(-2.0f, acc[m][n][j], cn);
                        t2_update(sv, col, rv1[m][j], ri1[m][j], rv2[m][j], ri2[m][j]);
                    }
                    f32x4 z = {0.f,0.f,0.f,0.f};
                    acc[m][n] = z;
                }
            }
        }
    }
    #undef STAGE_B

    // cross-lane top-2 merge over the 16 l15 lanes (ONCE per block)
    #pragma unroll
    for (int m = 0; m < 4; ++m)
        #pragma unroll
        for (int j = 0; j < 4; ++j) {
            #pragma unroll
            for (int off = 1; off <= 8; off <<= 1) {
                float b1 = __shfl_xor(rv1[m][j], off);
                float b2 = __shfl_xor(rv2[m][j], off);
                int  bi1 = __shfl_xor(ri1[m][j], off);
                int  bi2 = __shfl_xor(ri2[m][j], off);
                t2_merge(b1, bi1, b2, bi2, rv1[m][j], ri1[m][j], rv2[m][j], ri2[m][j]);
            }
        }

    // cross-wave merge over 8 cg groups via LDS; write global top-2 per row
    float4* red = (float4*)&lds[0];    // [64 rows][8 cg]
    __syncthreads();
    if (l15 == 0) {
        #pragma unroll
        for (int m = 0; m < 4; ++m)
            #pragma unroll
            for (int j = 0; j < 4; ++j) {
                const int rl = m*16 + lg*4 + j;
                float4 w;
                w.x = rv1[m][j]; w.y = __int_as_float(ri1[m][j]);
                w.z = rv2[m][j]; w.w = __int_as_float(ri2[m][j]);
                red[rl*8 + cg] = w;
            }
    }
    __syncthreads();
    if (t < 64) {
        float4 e0 = red[t*8 + 0];
        float v1 = e0.x, v2 = e0.z;
        int   i1 = __float_as_int(e0.y), i2 = __float_as_int(e0.w);
        #pragma unroll
        for (int w = 1; w < 8; ++w) {
            float4 e = red[t*8 + w];
            t2_merge(e.x, __float_as_int(e.y), e.z, __float_as_int(e.w), v1, i1, v2, i2);
        }
        pmini2[(rb*64 + t)*2 + 0] = i1;
        pmini2[(rb*64 + t)*2 + 1] = i2;
    }
}

// ---- kernel 3: exact fp64 resolve of the 2 candidates + write all outputs ----
__global__ __launch_bounds__(256) void vq_resolve_out(
    const float* __restrict__ X, const float* __restrict__ CB,
    const int* __restrict__ pmini2, float* __restrict__ out)
{
    const int wid  = threadIdx.x >> 6;
    const int lane = threadIdx.x & 63;
    const int row  = blockIdx.x * 4 + wid;
    const int i0 = pmini2[row*2 + 0], i1 = pmini2[row*2 + 1];

    const float4* xp = (const float4*)(X + (size_t)row * DDIM + lane * 8);
    float4 xa = xp[0], xb = xp[1];
    const float4* p0 = (const float4*)(CB + (size_t)i0 * DDIM + lane * 8);
    float4 c0a = p0[0], c0b = p0[1];
    const float4* p1 = (const float4*)(CB + (size_t)i1 * DDIM + lane * 8);
    float4 c1a = p1[0], c1b = p1[1];

    double d0 = 0.0, d1 = 0.0, e;
    e = (double)xa.x - c0a.x; d0 += e*e;  e = (double)xa.y - c0a.y; d0 += e*e;
    e = (double)xa.z - c0a.z; d0 += e*e;  e = (double)xa.w - c0a.w; d0 += e*e;
    e = (double)xb.x - c0b.x; d0 += e*e;  e = (double)xb.y - c0b.y; d0 += e*e;
    e = (double)xb.z - c0b.z; d0 += e*e;  e = (double)xb.w - c0b.w; d0 += e*e;
    e = (double)xa.x - c1a.x; d1 += e*e;  e = (double)xa.y - c1a.y; d1 += e*e;
    e = (double)xa.z - c1a.z; d1 += e*e;  e = (double)xa.w - c1a.w; d1 += e*e;
    e = (double)xb.x - c1b.x; d1 += e*e;  e = (double)xb.y - c1b.y; d1 += e*e;
    e = (double)xb.z - c1b.z; d1 += e*e;  e = (double)xb.w - c1b.w; d1 += e*e;
    #pragma unroll
    for (int off = 1; off < 64; off <<= 1) {
        d0 += __shfl_xor(d0, off);
        d1 += __shfl_xor(d1, off);
    }

    const bool w1 = (d1 < d0) || (d1 == d0 && i1 < i0);
    const int idxw = w1 ? i1 : i0;
    float4 qa, qb;
    qa.x = w1 ? c1a.x : c0a.x;  qa.y = w1 ? c1a.y : c0a.y;
    qa.z = w1 ? c1a.z : c0a.z;  qa.w = w1 ? c1a.w : c0a.w;
    qb.x = w1 ? c1b.x : c0b.x;  qb.y = w1 ? c1b.y : c0b.y;
    qb.z = w1 ? c1b.z : c0b.z;  qb.w = w1 ? c1b.w : c0b.w;

    float4 qoa, loa, qob, lob;
    float d, s;
    d = qa.x - xa.x; qoa.x = xa.x + d; s = d*d; loa.x = s + 0.25f*s;
    d = qa.y - xa.y; qoa.y = xa.y + d; s = d*d; loa.y = s + 0.25f*s;
    d = qa.z - xa.z; qoa.z = xa.z + d; s = d*d; loa.z = s + 0.25f*s;
    d = qa.w - xa.w; qoa.w = xa.w + d; s = d*d; loa.w = s + 0.25f*s;
    d = qb.x - xb.x; qob.x = xb.x + d; s = d*d; lob.x = s + 0.25f*s;
    d = qb.y - xb.y; qob.y = xb.y + d; s = d*d; lob.y = s + 0.25f*s;
    d = qb.z - xb.z; qob.z = xb.z + d; s = d*d; lob.z = s + 0.25f*s;
    d = qb.w - xb.w; qob.w = xb.w + d; s = d*d; lob.w = s + 0.25f*s;

    ((float4*)out)[(size_t)row*128 + lane*2 + 0] = qoa;
    ((float4*)out)[(size_t)row*128 + lane*2 + 1] = qob;
    ((float4*)(out + O_LOSS))[(size_t)row*128 + lane*2 + 0] = loa;
    ((float4*)(out + O_LOSS))[(size_t)row*128 + lane*2 + 1] = lob;
    if (lane == 0) out[O_IDX + row] = (float)idxw;
}

extern "C" void kernel_launch(void* const* d_in, const int* in_sizes, int n_in,
                              void* d_out, int out_size, void* d_ws, size_t ws_size,
                              hipStream_t stream)
{
    const float* X  = (const float*)d_in[0];
    const float* CB = (const float*)d_in[1];
    float* out = (float*)d_out;

    // big f16 scratch parked in out regions (all rewritten by the final kernels)
    char* XsB  = (char*)out;              // 32 MB swz8 f16 X   (qout region)
    char* CBsB = (char*)(out + O_LOSS);   //  8 MB swz8 f16 CB  (loss region)

    float* cnorm  = (float*)d_ws;             // 8192 floats
    int*   pmini2 = (int*)(cnorm + KCENT);    // 2*32768 ints

    vq_cvt_swz8<<<(NROWS*64)/256, 256, 0, stream>>>(X, XsB);
    vq_cvt_swz8<<<(KCENT*64)/256, 256, 0, stream>>>(CB, CBsB);
    vq_cnorm_kernel<<<KCENT/4, 256, 0, stream>>>(CB, cnorm, out + O_CNT);
    vq_sweep_kernel<<<NROWS/64, 512, 0, stream>>>(XsB, CBsB, cnorm, pmini2);
    vq_resolve_out<<<NROWS/4, 256, 0, stream>>>(X, CB, pmini2, out);
    hipMemcpyAsync(out + O_CBV, CB, (size_t)KCENT * DDIM * sizeof(float),
                   hipMemcpyDeviceToDevice, stream);
}

// Round 13
// 959.658 us; speedup vs baseline: 2.1392x; 2.1392x over previous
//
#include <hip/hip_runtime.h>

#define NROWS 32768
#define DDIM  512
#define KCENT 8192

// out layout (floats): qout[16777216] loss[16777216] idx[32768] cbv[4194304] counts[8192]
#define O_LOSS 16777216
#define O_IDX  33554432
#define O_CBV  33587200
#define O_CNT  37781504
#define O_PBLK 8388608      // float offset of pblk inside qout region (32 MB in)

typedef float f32x4 __attribute__((ext_vector_type(4)));
typedef _Float16 f16x8 __attribute__((ext_vector_type(8)));

// ---- kernel 0: fp32 -> f16, 8-slot XOR pre-swizzle within each 128B K-chunk ----
// slot u of (row r, chunk dk) holds logical unit u^(r&7)
__global__ __launch_bounds__(256) void vq_cvt_swz8(
    const float* __restrict__ src, char* __restrict__ dst)
{
    const int gid = blockIdx.x * 256 + threadIdx.x;   // one 16B f16 unit (8 floats)
    const int r = gid >> 6, w = gid & 63, dk = w >> 3, u = w & 7;
    const float4* p = (const float4*)(src + (size_t)r * DDIM + (dk*8 + (u ^ (r & 7))) * 8);
    float4 a = p[0], b = p[1];
    f16x8 h;
    h[0]=(_Float16)a.x; h[1]=(_Float16)a.y; h[2]=(_Float16)a.z; h[3]=(_Float16)a.w;
    h[4]=(_Float16)b.x; h[5]=(_Float16)b.y; h[6]=(_Float16)b.z; h[7]=(_Float16)b.w;
    *(f16x8*)(dst + (size_t)gid * 16) = h;
}

// ---- kernel 1: centroid squared norms (fp64 accumulate) + counts=1 ----
__global__ __launch_bounds__(256) void vq_cnorm_kernel(
    const float* __restrict__ CB, float* __restrict__ cnorm, float* __restrict__ counts)
{
    const int wid  = threadIdx.x >> 6;
    const int lane = threadIdx.x & 63;
    const int cid  = blockIdx.x * 4 + wid;
    const float4* p = (const float4*)(CB + (size_t)cid * DDIM + lane * 8);
    float4 a = p[0], b = p[1];
    double s = (double)a.x*a.x + (double)a.y*a.y + (double)a.z*a.z + (double)a.w*a.w
             + (double)b.x*b.x + (double)b.y*b.y + (double)b.z*b.z + (double)b.w*b.w;
    #pragma unroll
    for (int off = 32; off > 0; off >>= 1) s += __shfl_down(s, off);
    if (lane == 0) { cnorm[cid] = (float)s; counts[cid] = 1.0f; }
}

__device__ __forceinline__ void t2_update(float s, int c,
                                          float& v1, int& i1, float& v2, int& i2)
{
    if (s < v1)      { v2 = v1; i2 = i1; v1 = s; i1 = c; }
    else if (s < v2) { v2 = s;  i2 = c; }
}

__device__ __forceinline__ void t2_merge(float b1, int bi1, float b2, int bi2,
                                         float& a1, int& ai1, float& a2, int& ai2)
{
    if (b1 < a1 || (b1 == a1 && bi1 < ai1)) {
        float o1 = a1; int oi1 = ai1;
        a1 = b1; ai1 = bi1;
        if (b2 < o1 || (b2 == o1 && bi2 < oi1)) { a2 = b2; ai2 = bi2; }
        else                                    { a2 = o1; ai2 = oi1; }
    } else {
        if (b1 < a2 || (b1 == a2 && bi1 < ai2)) { a2 = b1; ai2 = bi1; }
    }
}

__device__ __forceinline__ void gl16(const char* g, const char* l)
{
    __builtin_amdgcn_global_load_lds(
        (const __attribute__((address_space(1))) void*)g,
        (__attribute__((address_space(3))) void*)l, 16, 0, 0);
}

// ---- kernel 2: m97-style 128x128 f16 GEMM tile + LDS-transpose top-2 epilogue ----
// 512 thr, 8 waves (2 row-groups x 4 col-groups); A/B staged via global_load_lds
// (linear dest, pre-swizzled global); XOR on ds_read -> conflict-free K-loop.
// Epilogue: scores -> LDS [128][132] f32, 4 threads/row scan 32 cols in-register.
__global__ __launch_bounds__(512, 4) void vq_gemm_kernel(
    const char* __restrict__ Xf, const char* __restrict__ Cf,
    const float* __restrict__ cnorm, float4* __restrict__ pblk)
{
    __shared__ __align__(16) char lds[67584];   // K-loop: A|B 32KB; epilogue: 128x132 f32

    // XCD mapping: xcd owns col-blocks [xcd*8, xcd*8+8) (1 MB CB slice, L2-resident)
    const int bid = blockIdx.x;
    const int xcd = bid & 7;
    const int idx = bid >> 3;            // 0..2047
    const int cb  = xcd * 8 + (idx & 7); // 0..63
    const int rb  = idx >> 3;            // 0..255

    const int t    = threadIdx.x;
    const int lane = t & 63;
    const int wid  = t >> 6;
    const int wr   = wid >> 2;    // 2 row-groups of 64
    const int wc   = wid & 3;     // 4 col-groups of 32
    const int l15  = lane & 15;
    const int lg   = lane >> 4;

    // staging: 1024 16B units per operand tile; thread covers units t and t+512
    const int r0 = t >> 3,         u0 = t & 7;
    const int r1 = (t + 512) >> 3, u1 = (t + 512) & 7;
    const size_t a0 = (size_t)(rb*128 + r0)*1024 + u0*16;
    const size_t a1 = (size_t)(rb*128 + r1)*1024 + u1*16;
    const size_t b0 = (size_t)(cb*128 + r0)*1024 + u0*16;
    const size_t b1 = (size_t)(cb*128 + r1)*1024 + u1*16;
    char* la0 = &lds[t*16];
    char* la1 = &lds[(t+512)*16];
    char* lb0 = &lds[16384 + t*16];
    char* lb1 = &lds[16384 + (t+512)*16];

    f32x4 z4 = {0.f, 0.f, 0.f, 0.f};
    f32x4 a00=z4, a01=z4, a10=z4, a11=z4, a20=z4, a21=z4, a30=z4, a31=z4;

    for (int dk = 0; dk < 8; ++dk) {
        __syncthreads();                       // prev compute done (no-op on dk=0)
        gl16(Xf + a0 + dk*128, la0);
        gl16(Xf + a1 + dk*128, la1);
        gl16(Cf + b0 + dk*128, lb0);
        gl16(Cf + b1 + dk*128, lb1);
        __syncthreads();                       // vmcnt(0) drain -> tiles visible

        #pragma unroll
        for (int ks = 0; ks < 2; ++ks) {
            const int ku = ks*4 + lg;          // logical 16B unit within the K-chunk
            const int rA0 = wr*64 +  0 + l15, rA1 = wr*64 + 16 + l15;
            const int rA2 = wr*64 + 32 + l15, rA3 = wr*64 + 48 + l15;
            const int rB0 = wc*32 +  0 + l15, rB1 = wc*32 + 16 + l15;
            f16x8 A0 = *(const f16x8*)(&lds[rA0*128 + ((ku ^ (rA0 & 7)) * 16)]);
            f16x8 A1 = *(const f16x8*)(&lds[rA1*128 + ((ku ^ (rA1 & 7)) * 16)]);
            f16x8 A2 = *(const f16x8*)(&lds[rA2*128 + ((ku ^ (rA2 & 7)) * 16)]);
            f16x8 A3 = *(const f16x8*)(&lds[rA3*128 + ((ku ^ (rA3 & 7)) * 16)]);
            f16x8 B0 = *(const f16x8*)(&lds[16384 + rB0*128 + ((ku ^ (rB0 & 7)) * 16)]);
            f16x8 B1 = *(const f16x8*)(&lds[16384 + rB1*128 + ((ku ^ (rB1 & 7)) * 16)]);
            a00 = __builtin_amdgcn_mfma_f32_16x16x32_f16(A0, B0, a00, 0, 0, 0);
            a01 = __builtin_amdgcn_mfma_f32_16x16x32_f16(A0, B1, a01, 0, 0, 0);
            a10 = __builtin_amdgcn_mfma_f32_16x16x32_f16(A1, B0, a10, 0, 0, 0);
            a11 = __builtin_amdgcn_mfma_f32_16x16x32_f16(A1, B1, a11, 0, 0, 0);
            a20 = __builtin_amdgcn_mfma_f32_16x16x32_f16(A2, B0, a20, 0, 0, 0);
            a21 = __builtin_amdgcn_mfma_f32_16x16x32_f16(A2, B1, a21, 0, 0, 0);
            a30 = __builtin_amdgcn_mfma_f32_16x16x32_f16(A3, B0, a30, 0, 0, 0);
            a31 = __builtin_amdgcn_mfma_f32_16x16x32_f16(A3, B1, a31, 0, 0, 0);
        }
    }
    __syncthreads();   // all compute done before LDS reuse for the score matrix

    // ---- epilogue phase 1: scores -> LDS [row][col], stride 132 floats ----
    float* sc = (float*)&lds[0];
    {
        const int colbase = cb*128 + wc*32;
        const float cn0 = cnorm[colbase + l15];
        const float cn1 = cnorm[colbase + 16 + l15];
        const int cl0 = wc*32 + l15, cl1 = wc*32 + 16 + l15;
        #define WSC(M, AC0, AC1)                                          \
            _Pragma("unroll")                                             \
            for (int j = 0; j < 4; ++j) {                                 \
                const int row = wr*64 + M*16 + lg*4 + j;                  \
                sc[row*132 + cl0] = fmaf(-2.0f, AC0[j], cn0);             \
                sc[row*132 + cl1] = fmaf(-2.0f, AC1[j], cn1);             \
            }
        WSC(0, a00, a01)
        WSC(1, a10, a11)
        WSC(2, a20, a21)
        WSC(3, a30, a31)
        #undef WSC
    }
    __syncthreads();

    // ---- epilogue phase 2: 4 threads/row scan 32 cols each, then 2-step merge ----
    {
        const int row = t >> 2;          // 0..127
        const int cq  = (t & 3) * 32;    // col quarter base
        const float* rp = sc + row*132 + cq;
        float v1 = 3.4e38f, v2 = 3.4e38f;
        int   i1 = 0x7fffffff, i2 = 0x7fffffff;
        #pragma unroll
        for (int q = 0; q < 8; ++q) {
            const float4 vv = *(const float4*)(rp + q*4);
            const int c4 = cb*128 + cq + q*4;
            t2_update(vv.x, c4 + 0, v1, i1, v2, i2);
            t2_update(vv.y, c4 + 1, v1, i1, v2, i2);
            t2_update(vv.z, c4 + 2, v1, i1, v2, i2);
            t2_update(vv.w, c4 + 3, v1, i1, v2, i2);
        }
        #pragma unroll
        for (int off = 1; off <= 2; off <<= 1) {
            float b1 = __shfl_xor(v1, off), b2 = __shfl_xor(v2, off);
            int  c1 = __shfl_xor(i1, off),  c2 = __shfl_xor(i2, off);
            t2_merge(b1, c1, b2, c2, v1, i1, v2, i2);
        }
        if ((t & 3) == 0) {
            float4 w; w.x = v1; w.y = __int_as_float(i1);
            w.z = v2; w.w = __int_as_float(i2);
            pblk[((size_t)(rb*128 + row))*64 + cb] = w;
        }
    }
}

// ---- kernel 3: merge 64 col-block top-2's per row -> global top-2 ----
__global__ __launch_bounds__(256) void vq_merge_kernel(
    const float4* __restrict__ pblk, int* __restrict__ pmini2)
{
    const int wid  = threadIdx.x >> 6;
    const int lane = threadIdx.x & 63;
    const int row  = blockIdx.x * 4 + wid;
    float4 e = pblk[(size_t)row*64 + lane];
    float v1 = e.x, v2 = e.z;
    int   i1 = __float_as_int(e.y), i2 = __float_as_int(e.w);
    #pragma unroll
    for (int off = 1; off < 64; off <<= 1) {
        float b1 = __shfl_xor(v1, off), b2 = __shfl_xor(v2, off);
        int  c1 = __shfl_xor(i1, off),  c2 = __shfl_xor(i2, off);
        t2_merge(b1, c1, b2, c2, v1, i1, v2, i2);
    }
    if (lane == 0) { pmini2[row*2 + 0] = i1; pmini2[row*2 + 1] = i2; }
}

// ---- kernel 4: exact fp64 resolve of the 2 candidates + write all outputs ----
__global__ __launch_bounds__(256) void vq_resolve_out(
    const float* __restrict__ X, const float* __restrict__ CB,
    const int* __restrict__ pmini2, float* __restrict__ out)
{
    const int wid  = threadIdx.x >> 6;
    const int lane = threadIdx.x & 63;
    const int row  = blockIdx.x * 4 + wid;
    const int i0 = pmini2[row*2 + 0], i1 = pmini2[row*2 + 1];

    const float4* xp = (const float4*)(X + (size_t)row * DDIM + lane * 8);
    float4 xa = xp[0], xb = xp[1];
    const float4* p0 = (const float4*)(CB + (size_t)i0 * DDIM + lane * 8);
    float4 c0a = p0[0], c0b = p0[1];
    const float4* p1 = (const float4*)(CB + (size_t)i1 * DDIM + lane * 8);
    float4 c1a = p1[0], c1b = p1[1];

    double d0 = 0.0, d1 = 0.0, e;
    e = (double)xa.x - c0a.x; d0 += e*e;  e = (double)xa.y - c0a.y; d0 += e*e;
    e = (double)xa.z - c0a.z; d0 += e*e;  e = (double)xa.w - c0a.w; d0 += e*e;
    e = (double)xb.x - c0b.x; d0 += e*e;  e = (double)xb.y - c0b.y; d0 += e*e;
    e = (double)xb.z - c0b.z; d0 += e*e;  e = (double)xb.w - c0b.w; d0 += e*e;
    e = (double)xa.x - c1a.x; d1 += e*e;  e = (double)xa.y - c1a.y; d1 += e*e;
    e = (double)xa.z - c1a.z; d1 += e*e;  e = (double)xa.w - c1a.w; d1 += e*e;
    e = (double)xb.x - c1b.x; d1 += e*e;  e = (double)xb.y - c1b.y; d1 += e*e;
    e = (double)xb.z - c1b.z; d1 += e*e;  e = (double)xb.w - c1b.w; d1 += e*e;
    #pragma unroll
    for (int off = 1; off < 64; off <<= 1) {
        d0 += __shfl_xor(d0, off);
        d1 += __shfl_xor(d1, off);
    }

    const bool w1 = (d1 < d0) || (d1 == d0 && i1 < i0);
    const int idxw = w1 ? i1 : i0;
    float4 qa, qb;
    qa.x = w1 ? c1a.x : c0a.x;  qa.y = w1 ? c1a.y : c0a.y;
    qa.z = w1 ? c1a.z : c0a.z;  qa.w = w1 ? c1a.w : c0a.w;
    qb.x = w1 ? c1b.x : c0b.x;  qb.y = w1 ? c1b.y : c0b.y;
    qb.z = w1 ? c1b.z : c0b.z;  qb.w = w1 ? c1b.w : c0b.w;

    float4 qoa, loa, qob, lob;
    float d, s;
    d = qa.x - xa.x; qoa.x = xa.x + d; s = d*d; loa.x = s + 0.25f*s;
    d = qa.y - xa.y; qoa.y = xa.y + d; s = d*d; loa.y = s + 0.25f*s;
    d = qa.z - xa.z; qoa.z = xa.z + d; s = d*d; loa.z = s + 0.25f*s;
    d = qa.w - xa.w; qoa.w = xa.w + d; s = d*d; loa.w = s + 0.25f*s;
    d = qb.x - xb.x; qob.x = xb.x + d; s = d*d; lob.x = s + 0.25f*s;
    d = qb.y - xb.y; qob.y = xb.y + d; s = d*d; lob.y = s + 0.25f*s;
    d = qb.z - xb.z; qob.z = xb.z + d; s = d*d; lob.z = s + 0.25f*s;
    d = qb.w - xb.w; qob.w = xb.w + d; s = d*d; lob.w = s + 0.25f*s;

    ((float4*)out)[(size_t)row*128 + lane*2 + 0] = qoa;
    ((float4*)out)[(size_t)row*128 + lane*2 + 1] = qob;
    ((float4*)(out + O_LOSS))[(size_t)row*128 + lane*2 + 0] = loa;
    ((float4*)(out + O_LOSS))[(size_t)row*128 + lane*2 + 1] = lob;
    if (lane == 0) out[O_IDX + row] = (float)idxw;
}

extern "C" void kernel_launch(void* const* d_in, const int* in_sizes, int n_in,
                              void* d_out, int out_size, void* d_ws, size_t ws_size,
                              hipStream_t stream)
{
    const float* X  = (const float*)d_in[0];
    const float* CB = (const float*)d_in[1];
    float* out = (float*)d_out;

    // big scratch parked in out regions (all rewritten by the final kernels)
    char*   XsB  = (char*)out;                    // 32 MB f16 X      (qout front half)
    float4* pblk = (float4*)(out + O_PBLK);       // 32 MB top-2/blk  (qout back half)
    char*   CBsB = (char*)(out + O_LOSS);         //  8 MB f16 CB     (loss region)

    float* cnorm  = (float*)d_ws;                 // 8192 floats
    int*   pmini2 = (int*)(cnorm + KCENT);        // 2*32768 ints

    vq_cvt_swz8<<<(NROWS*64)/256, 256, 0, stream>>>(X, XsB);
    vq_cvt_swz8<<<(KCENT*64)/256, 256, 0, stream>>>(CB, CBsB);
    vq_cnorm_kernel<<<KCENT/4, 256, 0, stream>>>(CB, cnorm, out + O_CNT);
    vq_gemm_kernel<<<(NROWS/128)*(KCENT/128), 512, 0, stream>>>(XsB, CBsB, cnorm, pblk);
    vq_merge_kernel<<<NROWS/4, 256, 0, stream>>>(pblk, pmini2);
    vq_resolve_out<<<NROWS/4, 256, 0, stream>>>(X, CB, pmini2, out);
    hipMemcpyAsync(out + O_CBV, CB, (size_t)KCENT * DDIM * sizeof(float),
                   hipMemcpyDeviceToDevice, stream);
}

// Round 14
// 905.052 us; speedup vs baseline: 2.2683x; 1.0603x over previous
//
#include <hip/hip_runtime.h>

#define NROWS 32768
#define DDIM  512
#define KCENT 8192

// out layout (floats): qout[16777216] loss[16777216] idx[32768] cbv[4194304] counts[8192]
#define O_LOSS 16777216
#define O_IDX  33554432
#define O_CBV  33587200
#define O_CNT  37781504
#define O_PBLK 8388608      // float offset of pblk inside qout region (32 MB in)

typedef float f32x4 __attribute__((ext_vector_type(4)));
typedef _Float16 f16x8 __attribute__((ext_vector_type(8)));

// ---- kernel 0: fp32 -> f16, 8-slot XOR pre-swizzle within each 128B K-chunk ----
// slot u of (row r, chunk dk) holds logical unit u^(r&7)
__global__ __launch_bounds__(256) void vq_cvt_swz8(
    const float* __restrict__ src, char* __restrict__ dst)
{
    const int gid = blockIdx.x * 256 + threadIdx.x;   // one 16B f16 unit (8 floats)
    const int r = gid >> 6, w = gid & 63, dk = w >> 3, u = w & 7;
    const float4* p = (const float4*)(src + (size_t)r * DDIM + (dk*8 + (u ^ (r & 7))) * 8);
    float4 a = p[0], b = p[1];
    f16x8 h;
    h[0]=(_Float16)a.x; h[1]=(_Float16)a.y; h[2]=(_Float16)a.z; h[3]=(_Float16)a.w;
    h[4]=(_Float16)b.x; h[5]=(_Float16)b.y; h[6]=(_Float16)b.z; h[7]=(_Float16)b.w;
    *(f16x8*)(dst + (size_t)gid * 16) = h;
}

// ---- kernel 1: centroid squared norms (fp64 accumulate) + counts=1 ----
__global__ __launch_bounds__(256) void vq_cnorm_kernel(
    const float* __restrict__ CB, float* __restrict__ cnorm, float* __restrict__ counts)
{
    const int wid  = threadIdx.x >> 6;
    const int lane = threadIdx.x & 63;
    const int cid  = blockIdx.x * 4 + wid;
    const float4* p = (const float4*)(CB + (size_t)cid * DDIM + lane * 8);
    float4 a = p[0], b = p[1];
    double s = (double)a.x*a.x + (double)a.y*a.y + (double)a.z*a.z + (double)a.w*a.w
             + (double)b.x*b.x + (double)b.y*b.y + (double)b.z*b.z + (double)b.w*b.w;
    #pragma unroll
    for (int off = 32; off > 0; off >>= 1) s += __shfl_down(s, off);
    if (lane == 0) { cnorm[cid] = (float)s; counts[cid] = 1.0f; }
}

__device__ __forceinline__ void t2_update(float s, int c,
                                          float& v1, int& i1, float& v2, int& i2)
{
    if (s < v1)      { v2 = v1; i2 = i1; v1 = s; i1 = c; }
    else if (s < v2) { v2 = s;  i2 = c; }
}

__device__ __forceinline__ void t2_merge(float b1, int bi1, float b2, int bi2,
                                         float& a1, int& ai1, float& a2, int& ai2)
{
    if (b1 < a1 || (b1 == a1 && bi1 < ai1)) {
        float o1 = a1; int oi1 = ai1;
        a1 = b1; ai1 = bi1;
        if (b2 < o1 || (b2 == o1 && bi2 < oi1)) { a2 = b2; ai2 = bi2; }
        else                                    { a2 = o1; ai2 = oi1; }
    } else {
        if (b1 < a2 || (b1 == a2 && bi1 < ai2)) { a2 = b1; ai2 = bi1; }
    }
}

__device__ __forceinline__ void gl16(const char* g, const char* l)
{
    __builtin_amdgcn_global_load_lds(
        (const __attribute__((address_space(1))) void*)g,
        (__attribute__((address_space(3))) void*)l, 16, 0, 0);
}

// ---- kernel 2: 128x128 f16 GEMM tile, 4 waves of 64x64 (m4 x n4) ----
// 256 thr; A/B via global_load_lds (linear dest, pre-swizzled global);
// XOR on ds_read -> conflict-free. 8 reads per 16 MFMA (0.5 ratio) and
// 4 blocks/CU (launch_bounds(256,4), LDS 4x32KB=128KB) -> LDS pipe relief
// + 4-way latency coverage. Shuffle epilogue (VALU idle at 13%).
__global__ __launch_bounds__(256, 4) void vq_gemm_kernel(
    const char* __restrict__ Xf, const char* __restrict__ Cf,
    const float* __restrict__ cnorm, float4* __restrict__ pblk)
{
    __shared__ __align__(16) char lds[32768];   // A[128][64]f16 | B[128][64]f16

    // XCD mapping: xcd owns col-blocks [xcd*8, xcd*8+8) (1 MB CB slice, L2-resident)
    const int bid = blockIdx.x;
    const int xcd = bid & 7;
    const int idx = bid >> 3;            // 0..2047
    const int cb  = xcd * 8 + (idx & 7); // 0..63
    const int rb  = idx >> 3;            // 0..255

    const int t    = threadIdx.x;        // 0..255
    const int lane = t & 63;
    const int wid  = t >> 6;             // 0..3
    const int wr   = wid >> 1;           // 2 row-groups of 64
    const int wc   = wid & 1;            // 2 col-groups of 64
    const int l15  = lane & 15;
    const int lg   = lane >> 4;

    // staging: 1024 16B units per operand; thread covers units t + i*256 (i=0..3)
    // (t+i*256)>>3 = (t>>3)+i*32 exactly, so src strides are constant 32KB.
    const size_t a0 = (size_t)(rb*128 + (t >> 3))*1024 + (t & 7)*16;
    const size_t b0 = (size_t)(cb*128 + (t >> 3))*1024 + (t & 7)*16;

    f32x4 acc[4][4];
    #pragma unroll
    for (int m = 0; m < 4; ++m)
        #pragma unroll
        for (int n = 0; n < 4; ++n) {
            f32x4 z = {0.f, 0.f, 0.f, 0.f};
            acc[m][n] = z;
        }

    for (int dk = 0; dk < 8; ++dk) {
        __syncthreads();                       // prev compute done (no-op on dk=0)
        #pragma unroll
        for (int i = 0; i < 4; ++i)
            gl16(Xf + a0 + i*32768 + dk*128, &lds[t*16 + i*4096]);
        #pragma unroll
        for (int i = 0; i < 4; ++i)
            gl16(Cf + b0 + i*32768 + dk*128, &lds[16384 + t*16 + i*4096]);
        __syncthreads();                       // staging drain -> tiles visible

        #pragma unroll
        for (int ks = 0; ks < 2; ++ks) {
            const int ku = ks*4 + lg;          // logical 16B unit within the K-chunk
            f16x8 A[4], B[4];
            #pragma unroll
            for (int m = 0; m < 4; ++m) {
                const int r = wr*64 + m*16 + l15;
                A[m] = *(const f16x8*)(&lds[r*128 + ((ku ^ (r & 7)) * 16)]);
            }
            #pragma unroll
            for (int n = 0; n < 4; ++n) {
                const int r = wc*64 + n*16 + l15;
                B[n] = *(const f16x8*)(&lds[16384 + r*128 + ((ku ^ (r & 7)) * 16)]);
            }
            #pragma unroll
            for (int m = 0; m < 4; ++m)
                #pragma unroll
                for (int n = 0; n < 4; ++n)
                    acc[m][n] = __builtin_amdgcn_mfma_f32_16x16x32_f16(A[m], B[n], acc[m][n], 0, 0, 0);
        }
    }
    __syncthreads();   // all compute done before LDS reuse for reduction

    // epilogue: per (m,j) row-slot, in-register top-2 over this wave's 64 cols
    // (4 n-frags), then 16-lane butterfly; 2 wc-waves merged via LDS.
    const int colbase = cb*128 + wc*64;
    float cn[4];
    int   cl[4];
    #pragma unroll
    for (int n = 0; n < 4; ++n) {
        cl[n] = colbase + n*16 + l15;
        cn[n] = cnorm[cl[n]];
    }
    float4* redq = (float4*)&lds[0];    // [128 rows][2 wc]

    #pragma unroll
    for (int m = 0; m < 4; ++m)
        #pragma unroll
        for (int j = 0; j < 4; ++j) {
            float v1 = 3.4e38f, v2 = 3.4e38f;
            int   i1 = 0x7fffffff, i2 = 0x7fffffff;
            #pragma unroll
            for (int n = 0; n < 4; ++n)
                t2_update(fmaf(-2.0f, acc[m][n][j], cn[n]), cl[n], v1, i1, v2, i2);
            #pragma unroll
            for (int off = 1; off <= 8; off <<= 1) {
                float e1 = __shfl_xor(v1, off), e2 = __shfl_xor(v2, off);
                int  f1 = __shfl_xor(i1, off),  f2 = __shfl_xor(i2, off);
                t2_merge(e1, f1, e2, f2, v1, i1, v2, i2);
            }
            if (l15 == 0) {
                float4 w; w.x = v1; w.y = __int_as_float(i1);
                w.z = v2; w.w = __int_as_float(i2);
                redq[(wr*64 + m*16 + lg*4 + j)*2 + wc] = w;
            }
        }

    __syncthreads();
    if (t < 128) {
        float4 e0 = redq[t*2 + 0], e1 = redq[t*2 + 1];
        float v1 = e0.x, v2 = e0.z;
        int   i1 = __float_as_int(e0.y), i2 = __float_as_int(e0.w);
        t2_merge(e1.x, __float_as_int(e1.y), e1.z, __float_as_int(e1.w), v1, i1, v2, i2);
        float4 w; w.x = v1; w.y = __int_as_float(i1); w.z = v2; w.w = __int_as_float(i2);
        pblk[((size_t)(rb*128 + t))*64 + cb] = w;
    }
}

// ---- kernel 3: merge 64 col-block top-2's per row -> global top-2 ----
__global__ __launch_bounds__(256) void vq_merge_kernel(
    const float4* __restrict__ pblk, int* __restrict__ pmini2)
{
    const int wid  = threadIdx.x >> 6;
    const int lane = threadIdx.x & 63;
    const int row  = blockIdx.x * 4 + wid;
    float4 e = pblk[(size_t)row*64 + lane];
    float v1 = e.x, v2 = e.z;
    int   i1 = __float_as_int(e.y), i2 = __float_as_int(e.w);
    #pragma unroll
    for (int off = 1; off < 64; off <<= 1) {
        float b1 = __shfl_xor(v1, off), b2 = __shfl_xor(v2, off);
        int  c1 = __shfl_xor(i1, off),  c2 = __shfl_xor(i2, off);
        t2_merge(b1, c1, b2, c2, v1, i1, v2, i2);
    }
    if (lane == 0) { pmini2[row*2 + 0] = i1; pmini2[row*2 + 1] = i2; }
}

// ---- kernel 4: exact fp64 resolve of the 2 candidates + write all outputs ----
__global__ __launch_bounds__(256) void vq_resolve_out(
    const float* __restrict__ X, const float* __restrict__ CB,
    const int* __restrict__ pmini2, float* __restrict__ out)
{
    const int wid  = threadIdx.x >> 6;
    const int lane = threadIdx.x & 63;
    const int row  = blockIdx.x * 4 + wid;
    const int i0 = pmini2[row*2 + 0], i1 = pmini2[row*2 + 1];

    const float4* xp = (const float4*)(X + (size_t)row * DDIM + lane * 8);
    float4 xa = xp[0], xb = xp[1];
    const float4* p0 = (const float4*)(CB + (size_t)i0 * DDIM + lane * 8);
    float4 c0a = p0[0], c0b = p0[1];
    const float4* p1 = (const float4*)(CB + (size_t)i1 * DDIM + lane * 8);
    float4 c1a = p1[0], c1b = p1[1];

    double d0 = 0.0, d1 = 0.0, e;
    e = (double)xa.x - c0a.x; d0 += e*e;  e = (double)xa.y - c0a.y; d0 += e*e;
    e = (double)xa.z - c0a.z; d0 += e*e;  e = (double)xa.w - c0a.w; d0 += e*e;
    e = (double)xb.x - c0b.x; d0 += e*e;  e = (double)xb.y - c0b.y; d0 += e*e;
    e = (double)xb.z - c0b.z; d0 += e*e;  e = (double)xb.w - c0b.w; d0 += e*e;
    e = (double)xa.x - c1a.x; d1 += e*e;  e = (double)xa.y - c1a.y; d1 += e*e;
    e = (double)xa.z - c1a.z; d1 += e*e;  e = (double)xa.w - c1a.w; d1 += e*e;
    e = (double)xb.x - c1b.x; d1 += e*e;  e = (double)xb.y - c1b.y; d1 += e*e;
    e = (double)xb.z - c1b.z; d1 += e*e;  e = (double)xb.w - c1b.w; d1 += e*e;
    #pragma unroll
    for (int off = 1; off < 64; off <<= 1) {
        d0 += __shfl_xor(d0, off);
        d1 += __shfl_xor(d1, off);
    }

    const bool w1 = (d1 < d0) || (d1 == d0 && i1 < i0);
    const int idxw = w1 ? i1 : i0;
    float4 qa, qb;
    qa.x = w1 ? c1a.x : c0a.x;  qa.y = w1 ? c1a.y : c0a.y;
    qa.z = w1 ? c1a.z : c0a.z;  qa.w = w1 ? c1a.w : c0a.w;
    qb.x = w1 ? c1b.x : c0b.x;  qb.y = w1 ? c1b.y : c0b.y;
    qb.z = w1 ? c1b.z : c0b.z;  qb.w = w1 ? c1b.w : c0b.w;

    float4 qoa, loa, qob, lob;
    float d, s;
    d = qa.x - xa.x; qoa.x = xa.x + d; s = d*d; loa.x = s + 0.25f*s;
    d = qa.y - xa.y; qoa.y = xa.y + d; s = d*d; loa.y = s + 0.25f*s;
    d = qa.z - xa.z; qoa.z = xa.z + d; s = d*d; loa.z = s + 0.25f*s;
    d = qa.w - xa.w; qoa.w = xa.w + d; s = d*d; loa.w = s + 0.25f*s;
    d = qb.x - xb.x; qob.x = xb.x + d; s = d*d; lob.x = s + 0.25f*s;
    d = qb.y - xb.y; qob.y = xb.y + d; s = d*d; lob.y = s + 0.25f*s;
    d = qb.z - xb.z; qob.z = xb.z + d; s = d*d; lob.z = s + 0.25f*s;
    d = qb.w - xb.w; qob.w = xb.w + d; s = d*d; lob.w = s + 0.25f*s;

    ((float4*)out)[(size_t)row*128 + lane*2 + 0] = qoa;
    ((float4*)out)[(size_t)row*128 + lane*2 + 1] = qob;
    ((float4*)(out + O_LOSS))[(size_t)row*128 + lane*2 + 0] = loa;
    ((float4*)(out + O_LOSS))[(size_t)row*128 + lane*2 + 1] = lob;
    if (lane == 0) out[O_IDX + row] = (float)idxw;
}

extern "C" void kernel_launch(void* const* d_in, const int* in_sizes, int n_in,
                              void* d_out, int out_size, void* d_ws, size_t ws_size,
                              hipStream_t stream)
{
    const float* X  = (const float*)d_in[0];
    const float* CB = (const float*)d_in[1];
    float* out = (float*)d_out;

    // big scratch parked in out regions (all rewritten by the final kernels)
    char*   XsB  = (char*)out;                    // 32 MB f16 X      (qout front half)
    float4* pblk = (float4*)(out + O_PBLK);       // 32 MB top-2/blk  (qout back half)
    char*   CBsB = (char*)(out + O_LOSS);         //  8 MB f16 CB     (loss region)

    float* cnorm  = (float*)d_ws;                 // 8192 floats
    int*   pmini2 = (int*)(cnorm + KCENT);        // 2*32768 ints

    vq_cvt_swz8<<<(NROWS*64)/256, 256, 0, stream>>>(X, XsB);
    vq_cvt_swz8<<<(KCENT*64)/256, 256, 0, stream>>>(CB, CBsB);
    vq_cnorm_kernel<<<KCENT/4, 256, 0, stream>>>(CB, cnorm, out + O_CNT);
    vq_gemm_kernel<<<(NROWS/128)*(KCENT/128), 256, 0, stream>>>(XsB, CBsB, cnorm, pblk);
    vq_merge_kernel<<<NROWS/4, 256, 0, stream>>>(pblk, pmini2);
    vq_resolve_out<<<NROWS/4, 256, 0, stream>>>(X, CB, pmini2, out);
    hipMemcpyAsync(out + O_CBV, CB, (size_t)KCENT * DDIM * sizeof(float),
                   hipMemcpyDeviceToDevice, stream);
}